// Round 3
// baseline (34515.173 us; speedup 1.0000x reference)
//
#include <hip/hip_runtime.h>
#include <math.h>

#define B 4
#define SEQ 33
#define MAXLEN 32
#define D 640
#define NH 8
#define DH 80
#define NL 6
#define FF 2560
#define V 30000
#define INITLEN 8
#define NBLK 1024
#define NT 256
#define EOS_TOK 2
#define NR_P 36
#define LM_NB 938   // ceil(30000/32)

struct Par {
  const int* iw;
  const float* emb;
  const float *Wq, *bq, *Wk, *bk, *Wv, *bv, *Wo, *bo;
  const float *ln1s, *ln1b, *W1, *b1, *W2, *b2, *ln2s, *ln2b, *lmW, *lmb;
  int* out;
};

// ---------------- persistent device scratch ----------------------------------
__device__ float g_Kc[(size_t)NL * B * NH * SEQ * DH];
__device__ float g_Vc[(size_t)NL * B * NH * SEQ * DH];
// decode
__device__ float g_x[B * D];          // layer input rows (LN2 of prev / emb)
__device__ float g_h1[B * D];         // LN1 rows
__device__ float g_xf[B * D];         // final LN2 rows for LM
__device__ float g_q[NH * B * DH];    // q finals
__device__ float g_opart[(size_t)NH * D * B];    // Wo partials (8 per col)
__device__ float g_f1[(size_t)FF * B];           // relu(FFN1) finals
__device__ float g_f2p[(size_t)8 * D * B];       // FFN2 partials (8 per col)
// prefill (36 rows = pos*4+b)
__device__ float g_xp[NR_P * D];
__device__ float g_h1p[NR_P * D];
__device__ float g_qP[(size_t)NH * NR_P * DH];
__device__ float g_opartP[(size_t)NH * D * NR_P];
__device__ float g_f1P[(size_t)FF * NR_P];
__device__ float g_f2pP[(size_t)8 * D * NR_P];
// control
__device__ unsigned long long g_keys[(size_t)LM_NB * B];
__device__ int g_tokens[B * SEQ];
__device__ int g_tok[B];
__device__ int g_stop;
__device__ unsigned g_flags[2048];
__device__ unsigned g_arrive = 0;
__device__ unsigned g_gen = 0;

#define KCIDX(l,b,h,pos,j) (((((size_t)(l)*B+(b))*NH+(h))*SEQ+(pos))*DH+(j))

// ---------------- init-time full grid barrier --------------------------------
__device__ __forceinline__ void gsync_full() {
  __syncthreads();
  if (threadIdx.x == 0) {
    __threadfence();
    unsigned g = __hip_atomic_load(&g_gen, __ATOMIC_SEQ_CST, __HIP_MEMORY_SCOPE_AGENT);
    unsigned old = __hip_atomic_fetch_add(&g_arrive, 1u, __ATOMIC_SEQ_CST, __HIP_MEMORY_SCOPE_AGENT);
    if (old == NBLK - 1u) {
      __hip_atomic_store(&g_arrive, 0u, __ATOMIC_SEQ_CST, __HIP_MEMORY_SCOPE_AGENT);
      __hip_atomic_fetch_add(&g_gen, 1u, __ATOMIC_SEQ_CST, __HIP_MEMORY_SCOPE_AGENT);
    } else {
      while (__hip_atomic_load(&g_gen, __ATOMIC_RELAXED, __HIP_MEMORY_SCOPE_AGENT) == g)
        __builtin_amdgcn_s_sleep(2);
    }
    __threadfence();
  }
  __syncthreads();
}

// ---------------- flag-based stage sync --------------------------------------
__device__ __forceinline__ void stage_done(int idx) {
  __syncthreads();
  if (threadIdx.x == 0) {
    __threadfence();
    __hip_atomic_fetch_add(&g_flags[idx], 1u, __ATOMIC_RELEASE, __HIP_MEMORY_SCOPE_AGENT);
  }
}
__device__ __forceinline__ void stage_wait(int idx, unsigned cnt) {
  if (threadIdx.x == 0) {
    int spins = 0;
    while (__hip_atomic_load(&g_flags[idx], __ATOMIC_RELAXED, __HIP_MEMORY_SCOPE_AGENT) < cnt) {
      if (spins < 256) __builtin_amdgcn_s_sleep(1);
      else             __builtin_amdgcn_s_sleep(8);
      ++spins;
    }
    __threadfence();
  }
  __syncthreads();
}

// ---------------- reduction / LN helpers -------------------------------------
__device__ __forceinline__ float bred_sum(float v, float* s_red) {
  #pragma unroll
  for (int o = 32; o > 0; o >>= 1) v += __shfl_down(v, o, 64);
  __syncthreads();
  if ((threadIdx.x & 63) == 0) s_red[threadIdx.x >> 6] = v;
  __syncthreads();
  return s_red[0] + s_red[1] + s_red[2] + s_red[3];
}

__device__ void ln_inplace(float* row, const float* gam, const float* bet, float* s_red) {
  float ps = 0.f;
  for (int d = threadIdx.x; d < D; d += NT) ps += row[d];
  const float m = bred_sum(ps, s_red) * (1.0f / 640.0f);
  float pv = 0.f;
  for (int d = threadIdx.x; d < D; d += NT) { float t = row[d] - m; pv += t * t; }
  const float var = bred_sum(pv, s_red) * (1.0f / 640.0f);
  const float rstd = 1.0f / sqrtf(var + 1e-6f);
  for (int d = threadIdx.x; d < D; d += NT)
    row[d] = (row[d] - m) * rstd * gam[d] + bet[d];
  __syncthreads();
}

// per-wave residual+LN builder: 4 rows, wave w handles row/batch b=w.
// parts: [(c*640+col)*4 + b], 8 partial sets.
__device__ void build_rows_ln(const float* resid, const float* bias, const float* parts,
                              const float* gam, const float* bet, float* s_rows) {
  const int tid = threadIdx.x, b = tid >> 6, lane = tid & 63;
  float v[10];
  #pragma unroll
  for (int k = 0; k < 10; ++k) {
    const int col = lane + 64 * k;
    float a = resid[b * 640 + col] + bias[col];
    #pragma unroll
    for (int c = 0; c < 8; ++c) a += parts[((size_t)c * 640 + col) * 4 + b];
    v[k] = a;
  }
  float s = 0.f;
  #pragma unroll
  for (int k = 0; k < 10; ++k) s += v[k];
  #pragma unroll
  for (int o = 32; o > 0; o >>= 1) s += __shfl_xor(s, o, 64);
  const float m = s * (1.0f / 640.0f);
  float q = 0.f;
  #pragma unroll
  for (int k = 0; k < 10; ++k) { const float d2 = v[k] - m; q += d2 * d2; }
  #pragma unroll
  for (int o = 32; o > 0; o >>= 1) q += __shfl_xor(q, o, 64);
  const float rstd = 1.0f / sqrtf(q * (1.0f / 640.0f) + 1e-6f);
  #pragma unroll
  for (int k = 0; k < 10; ++k) {
    const int col = lane + 64 * k;
    s_rows[b * 640 + col] = (v[k] - m) * rstd * gam[col] + bet[col];
  }
}

// =================== DECODE STAGES ===========================================
// Q: blocks [96,216). 120 blocks x 16 cols of the 1920 qkv cols, full depth.
__device__ void d_Q(const Par& p, int l, int pos, int fdep, float* smem) {
  const int idx = blockIdx.x - 96, tid = threadIdx.x;
  const int m = idx / 40, jbase = (idx % 40) * 16;
  const int dg = tid >> 4, cj = tid & 15, jcol = jbase + cj;
  const float* Wb = (m == 0 ? p.Wq : m == 1 ? p.Wk : p.Wv) + (size_t)l * D * D + jcol;
  float w[40];
  #pragma unroll
  for (int dd = 0; dd < 40; ++dd) w[dd] = Wb[(size_t)(dg * 40 + dd) * D];
  if (l > 0) stage_wait(fdep, 160);
  float* s_x = smem;
  if (l == 0) {
    const int b = tid >> 6, lane = tid & 63;
    const float* e = p.emb + (size_t)g_tok[b] * D;
    #pragma unroll
    for (int k = 0; k < 10; ++k) s_x[b * 640 + lane + 64 * k] = e[lane + 64 * k];
  } else {
    build_rows_ln(g_h1, p.b2 + (size_t)(l - 1) * D, g_f2p,
                  p.ln2s + (size_t)(l - 1) * D, p.ln2b + (size_t)(l - 1) * D, s_x);
  }
  __syncthreads();
  if (idx == 0) { for (int i = tid; i < B * D; i += NT) g_x[i] = s_x[i]; }
  float a0 = 0, a1 = 0, a2 = 0, a3 = 0;
  const float* xr = s_x + dg * 40;
  #pragma unroll 8
  for (int dd = 0; dd < 40; ++dd) {
    const float wv = w[dd];
    a0 += xr[dd] * wv; a1 += xr[640 + dd] * wv;
    a2 += xr[1280 + dd] * wv; a3 += xr[1920 + dd] * wv;
  }
  __syncthreads();
  float* s_p = smem + 2560;
  float* tp = s_p + (dg * 16 + cj) * 4;
  tp[0] = a0; tp[1] = a1; tp[2] = a2; tp[3] = a3;
  __syncthreads();
  if (tid < 64) {
    const int c2 = tid >> 2, b = tid & 3, jc = jbase + c2, h = jc / 80, j2 = jc % 80;
    float a = (m == 0 ? p.bq : m == 1 ? p.bk : p.bv)[(size_t)l * D + jc];
    #pragma unroll
    for (int g2 = 0; g2 < 16; ++g2) a += s_p[(g2 * 16 + c2) * 4 + b];
    if (m == 0)      g_q[(h * 4 + b) * 80 + j2] = a;
    else if (m == 1) g_Kc[KCIDX(l, b, h, pos, j2)] = a;
    else             g_Vc[KCIDX(l, b, h, pos, j2)] = a;
  }
}

// AW: blocks [216,256). h=idx/5, cg=idx%5 (128 Wo cols), full 80 depth (2 dgroups).
__device__ void d_AW(const Par& p, int l, int pos, int fdep, float* smem) {
  const int idx = blockIdx.x - 216, tid = threadIdx.x;
  const int h = idx / 5, cg = idx % 5, colb = cg * 128;
  const int cl = tid & 127, dg = tid >> 7;
  const float* Wb = p.Wo + (size_t)l * D * D + (size_t)(h * 80 + dg * 40) * D + colb + cl;
  float w[40];
  #pragma unroll
  for (int dd = 0; dd < 40; ++dd) w[dd] = Wb[(size_t)dd * D];
  stage_wait(fdep, 120);
  float* s_q = smem, *s_o = smem + 320, *s_sc = smem + 640, *s_p = smem + 800;
  for (int i = tid; i < 320; i += NT) s_q[i] = g_q[h * 320 + i];
  __syncthreads();
  const int nk = pos + 1;
  for (int task = tid; task < 4 * nk; task += NT) {
    const int b = task / nk, kp = task % nk;
    const float* kk = g_Kc + KCIDX(l, b, h, kp, 0);
    const float* qq = s_q + b * 80;
    float s = 0.f;
    for (int j = 0; j < 80; ++j) s += qq[j] * kk[j];
    s_sc[b * 33 + kp] = s / 8.94427190999915878564f;
  }
  __syncthreads();
  if (tid < 4) {
    const int b = tid;
    float mx = -1e30f;
    for (int k = 0; k < nk; ++k) mx = fmaxf(mx, s_sc[b * 33 + k]);
    float sum = 0.f;
    for (int k = 0; k < nk; ++k) { const float e = expf(s_sc[b * 33 + k] - mx); s_sc[b * 33 + k] = e; sum += e; }
    s_sc[132 + b] = 1.0f / sum;
  }
  __syncthreads();
  for (int task = tid; task < 320; task += NT) {
    const int b = task / 80, j = task % 80;
    float acc = 0.f;
    for (int kp = 0; kp < nk; ++kp) acc += s_sc[b * 33 + kp] * g_Vc[KCIDX(l, b, h, kp, j)];
    s_o[task] = acc * s_sc[132 + b];
  }
  __syncthreads();
  float a0 = 0, a1 = 0, a2 = 0, a3 = 0;
  const float* orr = s_o + dg * 40;
  #pragma unroll 8
  for (int dd = 0; dd < 40; ++dd) {
    const float wv = w[dd];
    a0 += orr[dd] * wv; a1 += orr[80 + dd] * wv;
    a2 += orr[160 + dd] * wv; a3 += orr[240 + dd] * wv;
  }
  __syncthreads();
  float* tp = s_p + (dg * 128 + cl) * 4;
  tp[0] = a0; tp[1] = a1; tp[2] = a2; tp[3] = a3;
  __syncthreads();
  if (tid < 128) {
    #pragma unroll
    for (int b = 0; b < 4; ++b)
      g_opart[((size_t)h * 640 + colb + tid) * 4 + b] =
          s_p[tid * 4 + b] + s_p[(128 + tid) * 4 + b];
  }
}

// F1: blocks [256,416). 160 blocks x 16 FFN cols, full depth; fused residual+LN1.
__device__ void d_F1(const Par& p, int l, int fdep, float* smem) {
  const int idx = blockIdx.x - 256, tid = threadIdx.x;
  const int dg = tid >> 4, cj = tid & 15, fbase = idx * 16, fcol = fbase + cj;
  const float* Wb = p.W1 + (size_t)l * D * FF + fcol;
  float w[40];
  #pragma unroll
  for (int dd = 0; dd < 40; ++dd) w[dd] = Wb[(size_t)(dg * 40 + dd) * FF];
  stage_wait(fdep, 40);
  float* s_h = smem;
  build_rows_ln(g_x, p.bo + (size_t)l * D, g_opart,
                p.ln1s + (size_t)l * D, p.ln1b + (size_t)l * D, s_h);
  __syncthreads();
  if (idx == 0) { for (int i = tid; i < B * D; i += NT) g_h1[i] = s_h[i]; }
  float a0 = 0, a1 = 0, a2 = 0, a3 = 0;
  const float* xr = s_h + dg * 40;
  #pragma unroll 8
  for (int dd = 0; dd < 40; ++dd) {
    const float wv = w[dd];
    a0 += xr[dd] * wv; a1 += xr[640 + dd] * wv;
    a2 += xr[1280 + dd] * wv; a3 += xr[1920 + dd] * wv;
  }
  __syncthreads();
  float* s_p = smem + 2560;
  float* tp = s_p + (dg * 16 + cj) * 4;
  tp[0] = a0; tp[1] = a1; tp[2] = a2; tp[3] = a3;
  __syncthreads();
  if (tid < 64) {
    const int c2 = tid >> 2, b = tid & 3;
    float a = p.b1[(size_t)l * FF + fbase + c2];
    #pragma unroll
    for (int g2 = 0; g2 < 16; ++g2) a += s_p[(g2 * 16 + c2) * 4 + b];
    g_f1[((size_t)fbase + c2) * 4 + b] = fmaxf(a, 0.f);
  }
}

// F2: blocks [416,576). dc=idx/20 (320 depth), cg=idx%20 (32 cols).
__device__ void d_F2(const Par& p, int l, int fdep, float* smem) {
  const int idx = blockIdx.x - 416, tid = threadIdx.x;
  const int dc = idx / 20, cg = idx % 20;
  const int dg = tid >> 5, cj = tid & 31, col = cg * 32 + cj;
  const float* Wb = p.W2 + (size_t)l * FF * D + (size_t)(dc * 320 + dg * 40) * D + col;
  float w[40];
  #pragma unroll
  for (int dd = 0; dd < 40; ++dd) w[dd] = Wb[(size_t)dd * D];
  stage_wait(fdep, 160);
  float* s_f = smem;
  for (int i = tid; i < 1280; i += NT) s_f[i] = g_f1[(size_t)dc * 1280 + i];
  __syncthreads();
  float a0 = 0, a1 = 0, a2 = 0, a3 = 0;
  const float* fb = s_f + dg * 160;
  #pragma unroll 8
  for (int dd = 0; dd < 40; ++dd) {
    const float wv = w[dd];
    a0 += fb[dd * 4] * wv; a1 += fb[dd * 4 + 1] * wv;
    a2 += fb[dd * 4 + 2] * wv; a3 += fb[dd * 4 + 3] * wv;
  }
  __syncthreads();
  float* s_p = smem + 1280;
  float* tp = s_p + (dg * 32 + cj) * 4;
  tp[0] = a0; tp[1] = a1; tp[2] = a2; tp[3] = a3;
  __syncthreads();
  if (tid < 128) {
    const int c2 = tid >> 2, b = tid & 3;
    float a = 0.f;
    #pragma unroll
    for (int s2 = 0; s2 < 8; ++s2) a += s_p[(s2 * 32 + c2) * 4 + b];
    g_f2p[((size_t)dc * 640 + cg * 32 + c2) * 4 + b] = a;
  }
}

// RL: blocks [576,580). final residual+LN2 -> g_xf
__device__ void d_RL(const Par& p, int fdep, float* smem, float* s_red) {
  const int b = blockIdx.x - 576, tid = threadIdx.x;
  stage_wait(fdep, 160);
  float* s_row = smem;
  for (int col = tid; col < D; col += NT) {
    float a = g_h1[b * 640 + col] + p.b2[(size_t)(NL - 1) * D + col];
    #pragma unroll
    for (int dc = 0; dc < 8; ++dc) a += g_f2p[((size_t)dc * 640 + col) * 4 + b];
    s_row[col] = a;
  }
  __syncthreads();
  ln_inplace(s_row, p.ln2s + (size_t)(NL - 1) * D, p.ln2b + (size_t)(NL - 1) * D, s_red);
  for (int col = tid; col < D; col += NT) g_xf[b * 640 + col] = s_row[col];
}

// LM: blocks [0,938). 32 cols, 8 depth-groups of 80. Prefetch 80 regs pre-wait.
__device__ void d_LM(const Par& p, const float* src, int fdep, unsigned cnt,
                     float* smem, unsigned long long* s_key) {
  const int bid = blockIdx.x, tid = threadIdx.x;
  const int cj = tid & 31, sg = tid >> 5;
  const int col = bid * 32 + cj;
  float w[80];
  if (col < V) {
    const float* Wc = p.lmW + (size_t)sg * 80 * V + col;
    #pragma unroll
    for (int dd = 0; dd < 80; ++dd) w[dd] = Wc[(size_t)dd * V];
  } else {
    #pragma unroll
    for (int dd = 0; dd < 80; ++dd) w[dd] = 0.f;
  }
  stage_wait(fdep, cnt);
  float* s_xf = smem;
  for (int i = tid; i < B * D; i += NT) s_xf[i] = src[i];
  __syncthreads();
  float a0 = 0, a1 = 0, a2 = 0, a3 = 0;
  const float* xr = s_xf + sg * 80;
  #pragma unroll 8
  for (int dd = 0; dd < 80; ++dd) {
    const float wv = w[dd];
    a0 += xr[dd] * wv; a1 += xr[640 + dd] * wv;
    a2 += xr[1280 + dd] * wv; a3 += xr[1920 + dd] * wv;
  }
  __syncthreads();
  float* s_part = smem + 2560;
  float* tp = s_part + (sg * 32 + cj) * 4;
  tp[0] = a0; tp[1] = a1; tp[2] = a2; tp[3] = a3;
  __syncthreads();
  if (tid < 128) {
    const int c2 = tid >> 2, b = tid & 3, col2 = bid * 32 + c2;
    unsigned long long key = 0ull;
    if (col2 < V) {
      float a = p.lmb[col2];
      #pragma unroll
      for (int s2 = 0; s2 < 8; ++s2) a += s_part[(s2 * 32 + c2) * 4 + b];
      unsigned u = __float_as_uint(a);
      u = (u & 0x80000000u) ? ~u : (u | 0x80000000u);
      key = ((unsigned long long)u << 32) | (unsigned)(V - col2);
    }
    s_key[c2 * 4 + b] = key;
  }
  __syncthreads();
  if (tid < 4) {
    unsigned long long k0 = 0ull;
    for (int c2 = 0; c2 < 32; ++c2) { const unsigned long long k = s_key[c2 * 4 + tid]; if (k > k0) k0 = k; }
    g_keys[(size_t)bid * 4 + tid] = k0;
  }
  __syncthreads();
}

// CTL: block 1023
__device__ void d_CTL(int t, int fdep, unsigned long long* s_key) {
  const int tid = threadIdx.x;
  stage_wait(fdep, LM_NB);
  for (int b = 0; b < B; ++b) {
    unsigned long long k = 0ull;
    for (int i = tid; i < LM_NB; i += NT) {
      const unsigned long long kk = g_keys[(size_t)i * 4 + b];
      if (kk > k) k = kk;
    }
    #pragma unroll
    for (int o = 32; o > 0; o >>= 1) {
      const unsigned long long kk = __shfl_down(k, o, 64);
      if (kk > k) k = kk;
    }
    __syncthreads();
    if ((tid & 63) == 0) s_key[tid >> 6] = k;
    __syncthreads();
    if (tid == 0) {
      unsigned long long k0 = s_key[0];
      #pragma unroll
      for (int q = 1; q < 4; ++q) if (s_key[q] > k0) k0 = s_key[q];
      const int tok = V - (int)(unsigned)(k0 & 0xFFFFFFFFull);
      g_tok[b] = tok;
      g_tokens[b * SEQ + t + 1] = tok;
    }
    __syncthreads();
  }
  if (tid == 0) {
    int stop = (t == MAXLEN - 1) ? 1 : 0;
    bool ae = true;
    for (int b = 0; b < B; ++b) ae = ae && (g_tok[b] == EOS_TOK);
    if (ae) stop = 1;
    g_stop = stop;
  }
}

// =================== PREFILL STAGES (36 rows) ================================
// Qp: blocks [0,360). qcg=idx/3 (16 cols), rg=idx%3 (12 rows).
__device__ void p_Qp(const Par& p, int l, int fdep, float* smem) {
  const int idx = blockIdx.x, tid = threadIdx.x;
  const int qcg = idx / 3, rg = idx % 3, r0 = rg * 12;
  const int m = qcg / 40, jbase = (qcg % 40) * 16;
  const int dg = tid >> 4, cj = tid & 15, jcol = jbase + cj;
  const float* Wb = (m == 0 ? p.Wq : m == 1 ? p.Wk : p.Wv) + (size_t)l * D * D + jcol;
  float w[40];
  #pragma unroll
  for (int dd = 0; dd < 40; ++dd) w[dd] = Wb[(size_t)(dg * 40 + dd) * D];
  if (l > 0) stage_wait(fdep, 36);
  float* s_xr = smem;
  for (int i = tid; i < 12 * 640; i += NT) s_xr[i] = g_xp[r0 * 640 + i];
  __syncthreads();
  float acc[12];
  #pragma unroll
  for (int rr = 0; rr < 12; ++rr) acc[rr] = 0.f;
  for (int dd = 0; dd < 40; ++dd) {
    const float wv = w[dd];
    const float* xc = s_xr + dg * 40 + dd;
    #pragma unroll
    for (int rr = 0; rr < 12; ++rr) acc[rr] += xc[rr * 640] * wv;
  }
  __syncthreads();
  float* s_p = smem;  // alias (x dead)
  float* tp = s_p + (dg * 16 + cj) * 12;
  #pragma unroll
  for (int rr = 0; rr < 12; ++rr) tp[rr] = acc[rr];
  __syncthreads();
  if (tid < 192) {
    const int c2 = tid / 12, rr = tid % 12, r = r0 + rr, pos = r >> 2, b = r & 3;
    const int jc = jbase + c2, h = jc / 80, j2 = jc % 80;
    float a = (m == 0 ? p.bq : m == 1 ? p.bk : p.bv)[(size_t)l * D + jc];
    #pragma unroll
    for (int g2 = 0; g2 < 16; ++g2) a += s_p[(g2 * 16 + c2) * 12 + rr];
    if (m == 0)      g_qP[((size_t)h * 36 + r) * 80 + j2] = a;
    else if (m == 1) g_Kc[KCIDX(l, b, h, pos, j2)] = a;
    else             g_Vc[KCIDX(l, b, h, pos, j2)] = a;
  }
}

// AWp: blocks [360,400). h=idx/5, cg=idx%5 (128 Wo cols); all 36 rows.
__device__ void p_AWp(const Par& p, int l, int fdep, float* smem) {
  const int idx = blockIdx.x - 360, tid = threadIdx.x;
  const int h = idx / 5, cg = idx % 5, colb = cg * 128;
  const int cl = tid & 127, dg = tid >> 7;
  const float* Wb = p.Wo + (size_t)l * D * D + (size_t)(h * 80 + dg * 40) * D + colb + cl;
  float w[40];
  #pragma unroll
  for (int dd = 0; dd < 40; ++dd) w[dd] = Wb[(size_t)dd * D];
  stage_wait(fdep, 360);
  float* s_qo = smem;          // 2880 (q, later o)
  float* s_sc = smem + 2880;   // 360
  float* s_p  = smem + 3328;   // 3072
  for (int i = tid; i < 2880; i += NT) s_qo[i] = g_qP[(size_t)h * 2880 + i];
  __syncthreads();
  for (int task = tid; task < 324; task += NT) {
    const int r = task / 9, kp = task % 9, pos = r >> 2, b = r & 3;
    if (kp <= pos) {
      const float* kk = g_Kc + KCIDX(l, b, h, kp, 0);
      const float* qq = s_qo + r * 80;
      float s = 0.f;
      for (int j = 0; j < 80; ++j) s += qq[j] * kk[j];
      s_sc[r * 9 + kp] = s / 8.94427190999915878564f;
    }
  }
  __syncthreads();
  if (tid < 36) {
    const int r = tid, pos = r >> 2;
    float mx = -1e30f;
    for (int k = 0; k <= pos; ++k) mx = fmaxf(mx, s_sc[r * 9 + k]);
    float sum = 0.f;
    for (int k = 0; k <= pos; ++k) { const float e = expf(s_sc[r * 9 + k] - mx); s_sc[r * 9 + k] = e; sum += e; }
    s_sc[324 + r] = 1.0f / sum;
  }
  __syncthreads();
  for (int task = tid; task < 2880; task += NT) {
    const int r = task / 80, j = task % 80, pos = r >> 2, b = r & 3;
    float acc = 0.f;
    for (int kp = 0; kp <= pos; ++kp) acc += s_sc[r * 9 + kp] * g_Vc[KCIDX(l, b, h, kp, j)];
    s_qo[task] = acc * s_sc[324 + r];   // o overwrites q (q dead)
  }
  __syncthreads();
  for (int pass = 0; pass < 3; ++pass) {
    const int rp0 = pass * 12;
    float acc[12];
    #pragma unroll
    for (int rr = 0; rr < 12; ++rr) acc[rr] = 0.f;
    for (int dd = 0; dd < 40; ++dd) {
      const float wv = w[dd];
      const float* oc = s_qo + rp0 * 80 + dg * 40 + dd;
      #pragma unroll
      for (int rr = 0; rr < 12; ++rr) acc[rr] += oc[rr * 80] * wv;
    }
    __syncthreads();
    float* tp = s_p + (dg * 128 + cl) * 12;
    #pragma unroll
    for (int rr = 0; rr < 12; ++rr) tp[rr] = acc[rr];
    __syncthreads();
    if (tid < 128) {
      for (int rr = 0; rr < 12; ++rr) {
        const float vv = s_p[tid * 12 + rr] + s_p[(128 + tid) * 12 + rr];
        g_opartP[((size_t)h * 640 + colb + tid) * 36 + rp0 + rr] = vv;
      }
    }
  }
}

// RFp: blocks [400,436): row r. residual + LN1 -> g_h1p
__device__ void p_RFp(const Par& p, int l, int fdep, float* smem, float* s_red) {
  const int r = blockIdx.x - 400, tid = threadIdx.x;
  stage_wait(fdep, 40);
  float* s_row = smem;
  for (int col = tid; col < D; col += NT) {
    float a = g_xp[r * 640 + col] + p.bo[(size_t)l * D + col];
    #pragma unroll
    for (int h = 0; h < 8; ++h) a += g_opartP[((size_t)h * 640 + col) * 36 + r];
    s_row[col] = a;
  }
  __syncthreads();
  ln_inplace(s_row, p.ln1s + (size_t)l * D, p.ln1b + (size_t)l * D, s_red);
  for (int col = tid; col < D; col += NT) g_h1p[r * 640 + col] = s_row[col];
}

// F1p: blocks [436,596): 16 FFN cols, 36 rows in 3 passes.
__device__ void p_F1p(const Par& p, int l, int fdep, float* smem) {
  const int idx = blockIdx.x - 436, tid = threadIdx.x;
  const int dg = tid >> 4, cj = tid & 15, fbase = idx * 16, fcol = fbase + cj;
  const float* Wb = p.W1 + (size_t)l * D * FF + fcol;
  float w[40];
  #pragma unroll
  for (int dd = 0; dd < 40; ++dd) w[dd] = Wb[(size_t)(dg * 40 + dd) * FF];
  stage_wait(fdep, 36);
  for (int pass = 0; pass < 3; ++pass) {
    const int r0 = pass * 12;
    __syncthreads();
    for (int i = tid; i < 7680; i += NT) smem[i] = g_h1p[r0 * 640 + i];
    __syncthreads();
    float acc[12];
    #pragma unroll
    for (int rr = 0; rr < 12; ++rr) acc[rr] = 0.f;
    for (int dd = 0; dd < 40; ++dd) {
      const float wv = w[dd];
      const float* xc = smem + dg * 40 + dd;
      #pragma unroll
      for (int rr = 0; rr < 12; ++rr) acc[rr] += xc[rr * 640] * wv;
    }
    __syncthreads();
    float* tp = smem + (dg * 16 + cj) * 12;  // alias
    #pragma unroll
    for (int rr = 0; rr < 12; ++rr) tp[rr] = acc[rr];
    __syncthreads();
    if (tid < 192) {
      const int c2 = tid / 12, rr = tid % 12;
      float a = p.b1[(size_t)l * FF + fbase + c2];
      #pragma unroll
      for (int g2 = 0; g2 < 16; ++g2) a += smem[(g2 * 16 + c2) * 12 + rr];
      g_f1P[((size_t)fbase + c2) * 36 + r0 + rr] = fmaxf(a, 0.f);
    }
  }
}

// F2p: blocks [596,756): dc=idx/20 (320 depth), cg=idx%20 (32 cols), 3 row passes.
__device__ void p_F2p(const Par& p, int l, int fdep, float* smem) {
  const int idx = blockIdx.x - 596, tid = threadIdx.x;
  const int dc = idx / 20, cg = idx % 20;
  const int dg = tid >> 5, cj = tid & 31, col = cg * 32 + cj;
  const float* Wb = p.W2 + (size_t)l * FF * D + (size_t)(dc * 320 + dg * 40) * D + col;
  float w[40];
  #pragma unroll
  for (int dd = 0; dd < 40; ++dd) w[dd] = Wb[(size_t)dd * D];
  stage_wait(fdep, 160);
  float* s_f = smem;          // 3840
  float* s_p = smem + 3840;   // 3072
  for (int pass = 0; pass < 3; ++pass) {
    const int r0 = pass * 12;
    __syncthreads();
    for (int i = tid; i < 3840; i += NT) {
      const int fj = i / 12, rr = i % 12;
      s_f[i] = g_f1P[((size_t)dc * 320 + fj) * 36 + r0 + rr];
    }
    __syncthreads();
    float acc[12];
    #pragma unroll
    for (int rr = 0; rr < 12; ++rr) acc[rr] = 0.f;
    for (int dd = 0; dd < 40; ++dd) {
      const float wv = w[dd];
      const float* fc = s_f + (dg * 40 + dd) * 12;
      #pragma unroll
      for (int rr = 0; rr < 12; ++rr) acc[rr] += fc[rr] * wv;
    }
    float* tp = s_p + (dg * 32 + cj) * 12;
    #pragma unroll
    for (int rr = 0; rr < 12; ++rr) tp[rr] = acc[rr];
    __syncthreads();
    for (int task = tid; task < 384; task += NT) {
      const int c2 = task / 12, rr = task % 12;
      float a = 0.f;
      #pragma unroll
      for (int s2 = 0; s2 < 8; ++s2) a += s_p[(s2 * 32 + c2) * 12 + rr];
      g_f2pP[((size_t)dc * 640 + cg * 32 + c2) * 36 + r0 + rr] = a;
    }
  }
}

// RQp: blocks [400,436): row r. residual + LN2 -> g_xp
__device__ void p_RQp(const Par& p, int l, int fdep, float* smem, float* s_red) {
  const int r = blockIdx.x - 400, tid = threadIdx.x;
  stage_wait(fdep, 160);
  float* s_row = smem;
  for (int col = tid; col < D; col += NT) {
    float a = g_h1p[r * 640 + col] + p.b2[(size_t)l * D + col];
    #pragma unroll
    for (int dc = 0; dc < 8; ++dc) a += g_f2pP[((size_t)dc * 640 + col) * 36 + r];
    s_row[col] = a;
  }
  __syncthreads();
  ln_inplace(s_row, p.ln2s + (size_t)l * D, p.ln2b + (size_t)l * D, s_red);
  for (int col = tid; col < D; col += NT) g_xp[r * 640 + col] = s_row[col];
}

// =================== MAIN ====================================================
__global__ __launch_bounds__(NT, 4) void tfgen(Par p) {
  __shared__ float smem[7808];
  __shared__ float s_red[4];
  __shared__ unsigned long long s_key[128];
  __shared__ int s_ctl;

  const int bid = blockIdx.x, tid = threadIdx.x;
  int ep = 0;

  // INIT
  if (tid < 2) g_flags[bid * 2 + tid] = 0u;
  if (bid < NR_P) {
    const int pos = bid >> 2, b = bid & 3;
    const int tk = (pos == 0) ? 1 : p.iw[b * INITLEN + pos - 1];
    for (int d = tid; d < D; d += NT) g_xp[bid * 640 + d] = p.emb[(size_t)tk * D + d];
  }
  if (bid == NBLK - 1) {
    for (int i = tid; i < B * SEQ; i += NT) {
      const int b = i / SEQ, pos = i % SEQ;
      int tk = 0;
      if (pos == 0) tk = 1;
      else if (pos <= INITLEN) tk = p.iw[b * INITLEN + pos - 1];
      g_tokens[i] = tk;
    }
  }
  gsync_full();

  // PREFILL
  int fPrev = -1;
  for (int l = 0; l < NL; ++l) {
    const int fQ = ep++;
    if (bid < 360) { p_Qp(p, l, fPrev, smem); stage_done(fQ); }
    const int fA = ep++;
    if (bid >= 360 && bid < 400) { p_AWp(p, l, fQ, smem); stage_done(fA); }
    const int fR = ep++;
    if (bid >= 400 && bid < 436) { p_RFp(p, l, fA, smem, s_red); stage_done(fR); }
    const int fF1 = ep++;
    if (bid >= 436 && bid < 596) { p_F1p(p, l, fR, smem); stage_done(fF1); }
    const int fF2 = ep++;
    if (bid >= 596 && bid < 756) { p_F2p(p, l, fF1, smem); stage_done(fF2); }
    const int fRQ = ep++;
    if (bid >= 400 && bid < 436) { p_RQp(p, l, fF2, smem, s_red); stage_done(fRQ); }
    fPrev = fRQ;
  }

  // DECODE
  int fLMdep = fPrev;
  unsigned fLMcnt = 36;
  for (int t = INITLEN;; ++t) {
    const int fLM = ep++;
    if (bid < LM_NB) {
      d_LM(p, (t == INITLEN) ? (g_xp + 32 * 640) : g_xf, fLMdep, fLMcnt, smem, s_key);
      stage_done(fLM);
    }
    const int fC = ep++;
    if (bid == NBLK - 1) { d_CTL(t, fLM, s_key); stage_done(fC); }
    stage_wait(fC, 1);
    if (tid == 0) s_ctl = g_stop;
    __syncthreads();
    if (s_ctl) break;

    const int pos = t + 1;
    int fF2 = -1;
    for (int l = 0; l < NL; ++l) {
      const int fQ = ep++;
      if (bid >= 96 && bid < 216) { d_Q(p, l, pos, fF2, smem); stage_done(fQ); }
      const int fA = ep++;
      if (bid >= 216 && bid < 256) { d_AW(p, l, pos, fQ, smem); stage_done(fA); }
      const int fF1 = ep++;
      if (bid >= 256 && bid < 416) { d_F1(p, l, fA, smem); stage_done(fF1); }
      fF2 = ep++;
      if (bid >= 416 && bid < 576) { d_F2(p, l, fF1, smem); stage_done(fF2); }
    }
    const int fRL = ep++;
    if (bid >= 576 && bid < 580) { d_RL(p, fF2, smem, s_red); stage_done(fRL); }
    fLMdep = fRL; fLMcnt = 4;
  }

  if (bid == 0) {
    for (int i = tid; i < B * MAXLEN; i += NT) {
      const int b = i >> 5, j = i & 31;
      p.out[i] = g_tokens[b * SEQ + j + 1];
    }
  }
}

extern "C" void kernel_launch(void* const* d_in, const int* in_sizes, int n_in,
                              void* d_out, int out_size, void* d_ws, size_t ws_size,
                              hipStream_t stream)
{
  (void)in_sizes; (void)n_in; (void)out_size; (void)d_ws; (void)ws_size;
  Par p;
  p.iw   = (const int*)  d_in[0];
  p.emb  = (const float*)d_in[2];
  p.Wq   = (const float*)d_in[3];  p.bq   = (const float*)d_in[4];
  p.Wk   = (const float*)d_in[5];  p.bk   = (const float*)d_in[6];
  p.Wv   = (const float*)d_in[7];  p.bv   = (const float*)d_in[8];
  p.Wo   = (const float*)d_in[9];  p.bo   = (const float*)d_in[10];
  p.ln1s = (const float*)d_in[11]; p.ln1b = (const float*)d_in[12];
  p.W1   = (const float*)d_in[13]; p.b1   = (const float*)d_in[14];
  p.W2   = (const float*)d_in[15]; p.b2   = (const float*)d_in[16];
  p.ln2s = (const float*)d_in[17]; p.ln2b = (const float*)d_in[18];
  p.lmW  = (const float*)d_in[19]; p.lmb  = (const float*)d_in[20];
  p.out  = (int*)d_out;

  void* args[] = { (void*)&p };
  hipError_t err = hipLaunchCooperativeKernel((const void*)tfgen, dim3(NBLK), dim3(NT),
                                              args, 0, stream);
  if (err != hipSuccess) {
    // __launch_bounds__(256,4) guarantees 4 blocks/CU co-residency on 256 CUs.
    hipLaunchKernelGGL(tfgen, dim3(NBLK), dim3(NT), 0, stream, p);
  }
}